// Round 6
// baseline (610.750 us; speedup 1.0000x reference)
//
#include <hip/hip_runtime.h>

typedef _Float16 half8 __attribute__((ext_vector_type(8)));
typedef float f32x4 __attribute__((ext_vector_type(4)));

#define DIM 256
#define NE 1024
#define NROWS 131072
#define DECAY 0.99f
#define ONE_MINUS 0.01f
#define EPS 1e-5f

// output offsets (floats) in d_out, concatenated in reference return order
#define OFF_Q    0u
#define OFF_DIFF 33554432u
#define OFF_IND  33554433u
#define OFF_NEMB 33685505u
#define OFF_NCS  33947649u
#define OFF_NEA  33948673u

#define GLOAD16(gp, lp) __builtin_amdgcn_global_load_lds( \
    (__attribute__((address_space(1))) const void*)(gp),  \
    (__attribute__((address_space(3))) void*)(lp), 16, 0, 0)

#define MFMA16(a, b, c) __builtin_amdgcn_mfma_f32_16x16x32_f16(a, b, c, 0, 0, 0)

// ---------------- K0: codebook transpose (LDS-tiled, coalesced both sides) ----
__global__ void k0_prep(const float* __restrict__ embed,
                        _Float16* __restrict__ bt_hi, _Float16* __restrict__ bt_lo,
                        float* __restrict__ embT) {
    __shared__ float T[64][65];
    int t = threadIdx.x;
    int j0 = blockIdx.x * 64, d0 = blockIdx.y * 64;
    #pragma unroll
    for (int p = 0; p < 16; ++p) {
        int dd = p * 4 + (t >> 6), jj = t & 63;
        T[jj][dd] = embed[(size_t)(d0 + dd) * NE + j0 + jj];
    }
    __syncthreads();
    #pragma unroll
    for (int p = 0; p < 16; ++p) {
        int jj = p * 4 + (t >> 6), dd = t & 63;
        float e = T[jj][dd];
        int j = j0 + jj, d = d0 + dd;
        embT[(size_t)j * DIM + d] = e;
        _Float16 h = (_Float16)e;
        bt_hi[(size_t)j * DIM + d] = h;
        bt_lo[(size_t)j * DIM + d] = (_Float16)(e - (float)h);
    }
}

// ---------------- K0b: sqh[j] = 0.5*||e_j||^2 ----------------
__global__ void k0b_sq(const float* __restrict__ embT, float* __restrict__ sqh) {
    int w = threadIdx.x >> 6, l = threadIdx.x & 63;
    int j = blockIdx.x * 4 + w;
    f32x4 v = *(const f32x4*)(embT + (size_t)j * DIM + l * 4);
    float s = v[0] * v[0] + v[1] * v[1] + v[2] * v[2] + v[3] * v[3];
    for (int off = 32; off; off >>= 1) s += __shfl_down(s, off);
    if (l == 0) sqh[j] = 0.5f * s;
}

// ---------------- K1: distance GEMM (16x16x32) + argmin + quantize + diff + hist ----
// 16 rows/wave (A hi/lo = 64 VGPR) -> 16 waves/CU; chunk = 16 codes (32KB dbuf
// LDS -> 4 blocks/CU); counted-vmcnt 2-deep prefetch; 4 accumulator chains.
__launch_bounds__(256, 4)
__global__ void k1_main(const float* __restrict__ input,
                        const _Float16* __restrict__ bt_hi,
                        const _Float16* __restrict__ bt_lo,
                        const float* __restrict__ embT,
                        const float* __restrict__ sqh,
                        float* __restrict__ out,
                        int* __restrict__ jint,
                        int* __restrict__ counts,
                        float* __restrict__ diffpart) {
    __shared__ _Float16 Bbuf[2][2][16][256];   // [buf][plane][code-row][k]  32 KB
    __shared__ float sq_lds[NE];               // 4 KB
    __shared__ float dred[4];

    const int tid = threadIdx.x;
    const int w  = tid >> 6;       // wave 0..3
    const int l  = tid & 63;       // lane
    const int lr = l & 15;         // M-row (A) / N-col (B) index within fragment
    const int lg = l >> 4;         // k-group (0..3), 8 k's each
    const int s7 = lr & 7;         // read-swizzle term
    const int row0 = blockIdx.x * 64 + w * 16;
    const int myrow = row0 + lr;

    // stage addressing: wave stages 4 x 1KB per chunk (rows 2w..2w+1 and 10+2w..)
    const int r0 = 2 * w + (l >> 5);        // dest row 0..7
    const int g0 = (l & 31) ^ r0;           // source granule (inverse swizzle)
    const int s0 = r0 * 256 + g0 * 8;       // f16 offset within plane-chunk
    const int s1 = s0 + 2048;               // rows 8..15

#define STAGE(cc, b) do {                                             \
    const _Float16* hp_ = bt_hi + (((size_t)(cc)) << 12);             \
    const _Float16* lp_ = bt_lo + (((size_t)(cc)) << 12);             \
    GLOAD16(hp_ + s0, &Bbuf[b][0][2 * w][0]);                         \
    GLOAD16(hp_ + s1, &Bbuf[b][0][8 + 2 * w][0]);                     \
    GLOAD16(lp_ + s0, &Bbuf[b][1][2 * w][0]);                         \
    GLOAD16(lp_ + s1, &Bbuf[b][1][8 + 2 * w][0]);                     \
} while (0)

    STAGE(0, 0);
    STAGE(1, 1);

    for (int i = tid; i < NE; i += 256) sq_lds[i] = sqh[i];

    // A load: lane holds row lr, dims {kf*32 + lg*8 + 0..7}, f16 hi/lo split.
    // Fully unrolled: all indices compile-time (rule #20).
    half8 ah[8], al[8];
    {
        const float* arow = input + (size_t)myrow * DIM + lg * 8;
        #pragma unroll
        for (int kf = 0; kf < 8; ++kf) {
            f32x4 x0 = *(const f32x4*)(arow + kf * 32);
            f32x4 x1 = *(const f32x4*)(arow + kf * 32 + 4);
            half8 hh, ll;
            #pragma unroll
            for (int i = 0; i < 4; ++i) {
                _Float16 h0 = (_Float16)x0[i];
                hh[i] = h0; ll[i] = (_Float16)(x0[i] - (float)h0);
                _Float16 h1 = (_Float16)x1[i];
                hh[4 + i] = h1; ll[4 + i] = (_Float16)(x1[i] - (float)h1);
            }
            ah[kf] = hh; al[kf] = ll;
        }
    }

    float best_val[4];
    int   best_idx[4];
    #pragma unroll
    for (int e = 0; e < 4; ++e) { best_val[e] = 3.4e38f; best_idx[e] = 0; }

    __syncthreads();   // one-time full drain: chunks 0,1 + sq_lds + A loads

    const int rb = lr * 256;
    int buf = 0;
    #pragma unroll 1
    for (int c = 0; c < 64; ++c) {
        // chunk c landed (own 4 oldest); chunk c+1 stays in flight
        if (c == 63) { asm volatile("s_waitcnt vmcnt(0)" ::: "memory"); }
        else         { asm volatile("s_waitcnt vmcnt(4)" ::: "memory"); }
        __builtin_amdgcn_s_barrier();

        const _Float16* BH = &Bbuf[buf][0][0][0];
        const _Float16* BL = &Bbuf[buf][1][0][0];

        f32x4 acc[4];
        #pragma unroll
        for (int e = 0; e < 4; ++e) acc[e] = (f32x4){0.f, 0.f, 0.f, 0.f};

        half8 bh[8], bl[8];
        __builtin_amdgcn_s_setprio(1);
        #pragma unroll
        for (int kf = 0; kf < 8; ++kf)
            bh[kf] = *(const half8*)(BH + rb + (((kf << 2) | lg) ^ s7) * 8);
        #pragma unroll
        for (int kf = 0; kf < 8; ++kf)
            acc[kf & 3] = MFMA16(ah[kf], bh[kf], acc[kf & 3]);
        #pragma unroll
        for (int kf = 0; kf < 8; ++kf)
            bl[kf] = *(const half8*)(BL + rb + (((kf << 2) | lg) ^ s7) * 8);
        #pragma unroll
        for (int kf = 0; kf < 8; ++kf)
            acc[kf & 3] = MFMA16(al[kf], bh[kf], acc[kf & 3]);
        #pragma unroll
        for (int kf = 0; kf < 8; ++kf)
            acc[kf & 3] = MFMA16(ah[kf], bl[kf], acc[kf & 3]);
        __builtin_amdgcn_s_setprio(0);
        __builtin_amdgcn_s_barrier();   // all waves done reading Bbuf[buf]

        // stage chunk c+2 into the buffer just consumed (2 iterations of cover)
        if (c < 62) STAGE(c + 2, buf);

        // register-only argmin update
        const int col = (c << 4) + lr;
        float sq = sq_lds[col];
        f32x4 dot = acc[0] + acc[1] + acc[2] + acc[3];
        #pragma unroll
        for (int e = 0; e < 4; ++e) {
            float v = sq - dot[e];
            if (v < best_val[e]) { best_val[e] = v; best_idx[e] = col; }
        }

        buf ^= 1;
    }

    // ---- cross-lane argmin within each 16-lane group (rows lg*4+e) ----
    #pragma unroll
    for (int e = 0; e < 4; ++e) {
        float v = best_val[e]; int ix = best_idx[e];
        #pragma unroll
        for (int off = 1; off < 16; off <<= 1) {
            float ov = __shfl_xor(v, off);
            int   oi = __shfl_xor(ix, off);
            if (ov < v || (ov == v && oi < ix)) { v = ov; ix = oi; }
        }
        best_val[e] = v; best_idx[e] = ix;
    }

    if (lr == 0) {
        #pragma unroll
        for (int e = 0; e < 4; ++e) {
            int grow = row0 + lg * 4 + e;
            int j = best_idx[e];
            out[OFF_IND + grow] = (float)j;
            jint[grow] = j;
            atomicAdd(&counts[j], 1);
        }
    }

    // winning code for THIS lane's A-row (row = lr)
    int jb[4];
    #pragma unroll
    for (int e = 0; e < 4; ++e) jb[e] = __shfl(best_idx[e], (lr >> 2) * 16);
    int rsel = lr & 3;
    int jm = jb[0];
    if (rsel == 1) jm = jb[1];
    else if (rsel == 2) jm = jb[2];
    else if (rsel == 3) jm = jb[3];

    // ---- quantize gather/write + diff partial (x rebuilt from ah+al) ----
    float dsum = 0.f;
    const float* qrow = embT + (size_t)jm * DIM + lg * 8;
    float* qout = out + OFF_Q + (size_t)myrow * DIM + lg * 8;
    #pragma unroll
    for (int kf = 0; kf < 8; ++kf) {
        f32x4 q0 = *(const f32x4*)(qrow + kf * 32);
        f32x4 q1 = *(const f32x4*)(qrow + kf * 32 + 4);
        *(f32x4*)(qout + kf * 32) = q0;
        *(f32x4*)(qout + kf * 32 + 4) = q1;
        #pragma unroll
        for (int i = 0; i < 4; ++i) {
            float x0 = (float)ah[kf][i] + (float)al[kf][i];
            float x1 = (float)ah[kf][4 + i] + (float)al[kf][4 + i];
            float d0 = q0[i] - x0, d1 = q1[i] - x1;
            dsum += d0 * d0 + d1 * d1;
        }
    }
    for (int off = 32; off; off >>= 1) dsum += __shfl_down(dsum, off);
    if (l == 0) dred[w] = dsum;
    __syncthreads();
    if (tid == 0) diffpart[blockIdx.x] = dred[0] + dred[1] + dred[2] + dred[3];
}

// ---------------- K2: shfl-scan + EMA scalars + diff finalize (1 block, 1024 thr) ----
__global__ void k2_small(const float* __restrict__ cluster_size,
                         const int* __restrict__ counts,
                         const float* __restrict__ diffpart,
                         float* __restrict__ out,
                         int* __restrict__ offsets,
                         float* __restrict__ cs_ws) {
    __shared__ int   wtot[16];
    __shared__ float wsum[16], wdiff[16];
    int t = threadIdx.x, w = t >> 6, l = t & 63;
    int cnt = counts[t];
    float ncs = cluster_size[t] * DECAY + ONE_MINUS * (float)cnt;
    out[OFF_NCS + t] = ncs;

    int sc = cnt;
    #pragma unroll
    for (int off = 1; off < 64; off <<= 1) {
        int v = __shfl_up(sc, off);
        if (l >= off) sc += v;
    }
    float ws = ncs;
    float dp = diffpart[t] + diffpart[t + 1024];   // k1 grid = 2048 blocks
    #pragma unroll
    for (int off = 32; off; off >>= 1) {
        ws += __shfl_xor(ws, off);
        dp += __shfl_xor(dp, off);
    }
    if (l == 63) wtot[w] = sc;
    if (l == 0) { wsum[w] = ws; wdiff[w] = dp; }
    __syncthreads();
    int woff = 0; float n = 0.f, dtot = 0.f;
    #pragma unroll
    for (int i = 0; i < 16; ++i) {
        woff += (i < w) ? wtot[i] : 0;
        n += wsum[i];
        dtot += wdiff[i];
    }
    offsets[t] = woff + sc - cnt;       // exclusive prefix
    cs_ws[t] = (ncs + EPS) / (n + (float)NE * EPS) * n;
    if (t == 0) out[OFF_DIFF] = dtot / 33554432.0f;
}

// ---------------- K3: scatter row ids into per-code buckets ----------------
__global__ void k3_scatter(const int* __restrict__ jint,
                           const int* __restrict__ offsets,
                           int* __restrict__ cursors,
                           int* __restrict__ list) {
    int r = blockIdx.x * 256 + threadIdx.x;
    int j = jint[r];
    int pos = atomicAdd(&cursors[j], 1);
    list[offsets[j] + pos] = r;
}

// ---------------- K4: BALANCED segment sum over sorted list ----------------
#define K4FLUSH() do {                                                   \
    float* dst = embed_sum + (size_t)curj * DIM + l * 4;                 \
    atomicAdd(dst + 0, acc[0]); atomicAdd(dst + 1, acc[1]);              \
    atomicAdd(dst + 2, acc[2]); atomicAdd(dst + 3, acc[3]);              \
    acc[0] = acc[1] = acc[2] = acc[3] = 0.f;                             \
} while (0)

__global__ void k4_segsum(const float* __restrict__ input,
                          const int* __restrict__ jint,
                          const int* __restrict__ list,
                          float* __restrict__ embed_sum) {
    int wid = (blockIdx.x * 256 + threadIdx.x) >> 6;   // 0..4095
    int l = threadIdx.x & 63;
    int p0 = wid * 32;
    int row_l = list[p0 + (l & 31)];
    int j_l = jint[row_l];
    f32x4 acc = {0.f, 0.f, 0.f, 0.f};
    int curj = __shfl(j_l, 0);
    #pragma unroll 1
    for (int g = 0; g < 8; ++g) {
        int r0 = __shfl(row_l, 4 * g + 0), j0 = __shfl(j_l, 4 * g + 0);
        int r1 = __shfl(row_l, 4 * g + 1), j1 = __shfl(j_l, 4 * g + 1);
        int r2 = __shfl(row_l, 4 * g + 2), j2 = __shfl(j_l, 4 * g + 2);
        int r3 = __shfl(row_l, 4 * g + 3), j3 = __shfl(j_l, 4 * g + 3);
        f32x4 v0 = *(const f32x4*)(input + (size_t)r0 * DIM + l * 4);
        f32x4 v1 = *(const f32x4*)(input + (size_t)r1 * DIM + l * 4);
        f32x4 v2 = *(const f32x4*)(input + (size_t)r2 * DIM + l * 4);
        f32x4 v3 = *(const f32x4*)(input + (size_t)r3 * DIM + l * 4);
        if (j0 != curj) { K4FLUSH(); curj = j0; }
        acc += v0;
        if (j1 != curj) { K4FLUSH(); curj = j1; }
        acc += v1;
        if (j2 != curj) { K4FLUSH(); curj = j2; }
        acc += v2;
        if (j3 != curj) { K4FLUSH(); curj = j3; }
        acc += v3;
    }
    K4FLUSH();
}

// ---------------- K5: transpose + EMA outputs (LDS-tiled, coalesced) ----------
__global__ void k5_ema(const float* __restrict__ embed_sum,
                       const float* __restrict__ embed_avg,
                       const float* __restrict__ cs_ws,
                       float* __restrict__ out) {
    __shared__ float T[64][65];
    int t = threadIdx.x;
    int j0 = blockIdx.x * 64, d0 = blockIdx.y * 64;
    #pragma unroll
    for (int p = 0; p < 16; ++p) {
        int jj = p * 4 + (t >> 6), dd = t & 63;
        T[dd][jj] = embed_sum[(size_t)(j0 + jj) * DIM + d0 + dd];
    }
    __syncthreads();
    #pragma unroll
    for (int p = 0; p < 16; ++p) {
        int dd = p * 4 + (t >> 6), jj = t & 63;
        int d = d0 + dd, j = j0 + jj;
        float sum = T[dd][jj];
        float na = embed_avg[(size_t)d * NE + j] * DECAY + ONE_MINUS * sum;
        out[OFF_NEA + (size_t)d * NE + j] = na;
        out[OFF_NEMB + (size_t)d * NE + j] = na / cs_ws[j];
    }
}

extern "C" void kernel_launch(void* const* d_in, const int* in_sizes, int n_in,
                              void* d_out, int out_size, void* d_ws, size_t ws_size,
                              hipStream_t stream) {
    const float* input        = (const float*)d_in[0];
    const float* embed        = (const float*)d_in[1];
    const float* cluster_size = (const float*)d_in[2];
    const float* embed_avg    = (const float*)d_in[3];
    float* out = (float*)d_out;
    char* ws = (char*)d_ws;

    _Float16* bt_hi  = (_Float16*)(ws + 0);
    _Float16* bt_lo  = (_Float16*)(ws + 524288);
    float*    embT   = (float*)(ws + 1048576);
    float*    sqh    = (float*)(ws + 2097152);
    int*      counts = (int*)(ws + 2101248);
    int*      offsets= (int*)(ws + 2105344);
    int*      cursors= (int*)(ws + 2113536);
    int*      jint   = (int*)(ws + 2117632);
    int*      list   = (int*)(ws + 2641920);
    float*    diffpart = (float*)(ws + 3166208);   // 2048 floats
    float*    cs_ws  = (float*)(ws + 3174400);
    // k4/k5 run after k1 is done with the f16 planes: reuse that 1 MB region
    float*    embed_sum = (float*)(ws + 0);   // [1024][256] f32

    hipMemsetAsync(counts, 0, 4096, stream);
    hipMemsetAsync(cursors, 0, 4096, stream);

    k0_prep<<<dim3(16, 4), 256, 0, stream>>>(embed, bt_hi, bt_lo, embT);
    k0b_sq<<<256, 256, 0, stream>>>(embT, sqh);
    k1_main<<<2048, 256, 0, stream>>>(input, bt_hi, bt_lo, embT, sqh, out, jint, counts, diffpart);
    // bt_hi/bt_lo dead after k1 -> zero that region for embed_sum accumulation
    hipMemsetAsync(embed_sum, 0, (size_t)NE * DIM * sizeof(float), stream);
    k2_small<<<1, 1024, 0, stream>>>(cluster_size, counts, diffpart, out, offsets, cs_ws);
    k3_scatter<<<512, 256, 0, stream>>>(jint, offsets, cursors, list);
    k4_segsum<<<1024, 256, 0, stream>>>(input, jint, list, embed_sum);
    k5_ema<<<dim3(16, 4), 256, 0, stream>>>(embed_sum, embed_avg, cs_ws, out);
}

// Round 7
// 463.919 us; speedup vs baseline: 1.3165x; 1.3165x over previous
//
#include <hip/hip_runtime.h>

typedef _Float16 half8 __attribute__((ext_vector_type(8)));
typedef float f32x4 __attribute__((ext_vector_type(4)));

#define DIM 256
#define NE 1024
#define NROWS 131072
#define DECAY 0.99f
#define ONE_MINUS 0.01f
#define EPS 1e-5f

// output offsets (floats) in d_out, concatenated in reference return order
#define OFF_Q    0u
#define OFF_DIFF 33554432u
#define OFF_IND  33554433u
#define OFF_NEMB 33685505u
#define OFF_NCS  33947649u
#define OFF_NEA  33948673u

#define GLOAD16(gp, lp) __builtin_amdgcn_global_load_lds( \
    (__attribute__((address_space(1))) const void*)(gp),  \
    (__attribute__((address_space(3))) void*)(lp), 16, 0, 0)

#define MFMA16(a, b, c) __builtin_amdgcn_mfma_f32_16x16x32_f16(a, b, c, 0, 0, 0)

// ---------------- K0: codebook transpose (LDS-tiled, coalesced both sides) ----
// embed [256][1024] -> bt_hi [1024][256] f16 hi plane + embT [1024][256] f32
__global__ void k0_prep(const float* __restrict__ embed,
                        _Float16* __restrict__ bt_hi,
                        float* __restrict__ embT) {
    __shared__ float T[64][65];
    int t = threadIdx.x;
    int j0 = blockIdx.x * 64, d0 = blockIdx.y * 64;
    #pragma unroll
    for (int p = 0; p < 16; ++p) {
        int dd = p * 4 + (t >> 6), jj = t & 63;
        T[jj][dd] = embed[(size_t)(d0 + dd) * NE + j0 + jj];
    }
    __syncthreads();
    #pragma unroll
    for (int p = 0; p < 16; ++p) {
        int jj = p * 4 + (t >> 6), dd = t & 63;
        float e = T[jj][dd];
        int j = j0 + jj, d = d0 + dd;
        embT[(size_t)j * DIM + d] = e;
        bt_hi[(size_t)j * DIM + d] = (_Float16)e;
    }
}

// ---------------- K0b: sqh[j] = 0.5*||e_j||^2 (exact f32) ----------------
__global__ void k0b_sq(const float* __restrict__ embT, float* __restrict__ sqh) {
    int w = threadIdx.x >> 6, l = threadIdx.x & 63;
    int j = blockIdx.x * 4 + w;
    f32x4 v = *(const f32x4*)(embT + (size_t)j * DIM + l * 4);
    float s = v[0] * v[0] + v[1] * v[1] + v[2] * v[2] + v[3] * v[3];
    for (int off = 32; off; off >>= 1) s += __shfl_down(s, off);
    if (l == 0) sqh[j] = 0.5f * s;
}

// ---------------- K1: distance GEMM (16x16x32, 2-term hi/lo-A x hi-B) ----------
// x.e ~= ah.bh + al.bh (B hi-plane only in LDS -> half LDS traffic, ~120 VGPR
// -> true 4 waves/SIMD). Counted-vmcnt 2-deep prefetch, 2 gload_lds/chunk/wave.
__launch_bounds__(256, 4)
__global__ void k1_main(const float* __restrict__ input,
                        const _Float16* __restrict__ bt_hi,
                        const float* __restrict__ embT,
                        const float* __restrict__ sqh,
                        float* __restrict__ out,
                        int* __restrict__ jint,
                        int* __restrict__ counts,
                        float* __restrict__ diffpart) {
    __shared__ _Float16 Bbuf[2][16][256];   // [buf][code-row][k]  16 KB
    __shared__ float sq_lds[NE];            // 4 KB
    __shared__ float dred[4];

    const int tid = threadIdx.x;
    const int w  = tid >> 6;       // wave 0..3
    const int l  = tid & 63;       // lane
    const int lr = l & 15;         // M-row (A) / N-col (B) within fragment
    const int lg = l >> 4;         // k-group (0..3)
    const int s7 = lr & 7;         // read-swizzle term
    const int row0 = blockIdx.x * 64 + w * 16;
    const int myrow = row0 + lr;

    // stage addressing: wave stages 2 x 1KB per chunk (hi plane only)
    const int r0 = 2 * w + (l >> 5);        // dest row 0..7
    const int g0 = (l & 31) ^ r0;           // source granule (inverse swizzle)
    const int s0 = r0 * 256 + g0 * 8;       // f16 offset within chunk
    const int s1 = s0 + 2048;               // rows 8..15

#define STAGE(cc, b) do {                                             \
    const _Float16* hp_ = bt_hi + (((size_t)(cc)) << 12);             \
    GLOAD16(hp_ + s0, &Bbuf[b][2 * w][0]);                            \
    GLOAD16(hp_ + s1, &Bbuf[b][8 + 2 * w][0]);                        \
} while (0)

    STAGE(0, 0);
    STAGE(1, 1);

    for (int i = tid; i < NE; i += 256) sq_lds[i] = sqh[i];

    // A load: lane holds row lr, dims {kf*32 + lg*8 + 0..7}, f16 hi/lo split.
    // Fully unrolled: all indices compile-time (rule #20).
    half8 ah[8], al[8];
    {
        const float* arow = input + (size_t)myrow * DIM + lg * 8;
        #pragma unroll
        for (int kf = 0; kf < 8; ++kf) {
            f32x4 x0 = *(const f32x4*)(arow + kf * 32);
            f32x4 x1 = *(const f32x4*)(arow + kf * 32 + 4);
            half8 hh, ll;
            #pragma unroll
            for (int i = 0; i < 4; ++i) {
                _Float16 h0 = (_Float16)x0[i];
                hh[i] = h0; ll[i] = (_Float16)(x0[i] - (float)h0);
                _Float16 h1 = (_Float16)x1[i];
                hh[4 + i] = h1; ll[4 + i] = (_Float16)(x1[i] - (float)h1);
            }
            ah[kf] = hh; al[kf] = ll;
        }
    }

    float best_val[4];
    int   best_idx[4];
    #pragma unroll
    for (int e = 0; e < 4; ++e) { best_val[e] = 3.4e38f; best_idx[e] = 0; }

    __syncthreads();   // one-time full drain: chunks 0,1 + sq_lds + A loads

    const int rb = lr * 256;
    int buf = 0;
    #pragma unroll 1
    for (int c = 0; c < 64; ++c) {
        // own 2 chunk-c loads landed; chunk c+1's stay in flight
        if (c == 63) { asm volatile("s_waitcnt vmcnt(0)" ::: "memory"); }
        else         { asm volatile("s_waitcnt vmcnt(2)" ::: "memory"); }
        __builtin_amdgcn_s_barrier();

        const _Float16* BH = &Bbuf[buf][0][0];

        f32x4 acc0 = {0.f,0.f,0.f,0.f}, acc1 = {0.f,0.f,0.f,0.f};
        f32x4 acc2 = {0.f,0.f,0.f,0.f}, acc3 = {0.f,0.f,0.f,0.f};

        __builtin_amdgcn_s_setprio(1);
        {   // kf 0..3: 4 reads, 8 MFMAs (chains 0-3, each written twice, spacing 4)
            half8 b0 = *(const half8*)(BH + rb + (((0 << 2) | lg) ^ s7) * 8);
            half8 b1 = *(const half8*)(BH + rb + (((1 << 2) | lg) ^ s7) * 8);
            half8 b2 = *(const half8*)(BH + rb + (((2 << 2) | lg) ^ s7) * 8);
            half8 b3 = *(const half8*)(BH + rb + (((3 << 2) | lg) ^ s7) * 8);
            acc0 = MFMA16(ah[0], b0, acc0);
            acc1 = MFMA16(ah[1], b1, acc1);
            acc2 = MFMA16(ah[2], b2, acc2);
            acc3 = MFMA16(ah[3], b3, acc3);
            acc0 = MFMA16(al[0], b0, acc0);
            acc1 = MFMA16(al[1], b1, acc1);
            acc2 = MFMA16(al[2], b2, acc2);
            acc3 = MFMA16(al[3], b3, acc3);
        }
        {   // kf 4..7
            half8 b0 = *(const half8*)(BH + rb + (((4 << 2) | lg) ^ s7) * 8);
            half8 b1 = *(const half8*)(BH + rb + (((5 << 2) | lg) ^ s7) * 8);
            half8 b2 = *(const half8*)(BH + rb + (((6 << 2) | lg) ^ s7) * 8);
            half8 b3 = *(const half8*)(BH + rb + (((7 << 2) | lg) ^ s7) * 8);
            acc0 = MFMA16(ah[4], b0, acc0);
            acc1 = MFMA16(ah[5], b1, acc1);
            acc2 = MFMA16(ah[6], b2, acc2);
            acc3 = MFMA16(ah[7], b3, acc3);
            acc0 = MFMA16(al[4], b0, acc0);
            acc1 = MFMA16(al[5], b1, acc1);
            acc2 = MFMA16(al[6], b2, acc2);
            acc3 = MFMA16(al[7], b3, acc3);
        }
        __builtin_amdgcn_s_setprio(0);
        __builtin_amdgcn_s_barrier();   // all waves done reading Bbuf[buf]

        // stage chunk c+2 into the buffer just consumed
        if (c < 62) STAGE(c + 2, buf);

        // register-only argmin update
        const int col = (c << 4) + lr;
        float sq = sq_lds[col];
        f32x4 dot = acc0 + acc1 + acc2 + acc3;
        #pragma unroll
        for (int e = 0; e < 4; ++e) {
            float v = sq - dot[e];
            if (v < best_val[e]) { best_val[e] = v; best_idx[e] = col; }
        }

        buf ^= 1;
    }

    // ---- cross-lane argmin within each 16-lane group (rows lg*4+e) ----
    #pragma unroll
    for (int e = 0; e < 4; ++e) {
        float v = best_val[e]; int ix = best_idx[e];
        #pragma unroll
        for (int off = 1; off < 16; off <<= 1) {
            float ov = __shfl_xor(v, off);
            int   oi = __shfl_xor(ix, off);
            if (ov < v || (ov == v && oi < ix)) { v = ov; ix = oi; }
        }
        best_val[e] = v; best_idx[e] = ix;
    }

    if (lr == 0) {
        #pragma unroll
        for (int e = 0; e < 4; ++e) {
            int grow = row0 + lg * 4 + e;
            int j = best_idx[e];
            out[OFF_IND + grow] = (float)j;
            jint[grow] = j;
            atomicAdd(&counts[j], 1);
        }
    }

    // winning code for THIS lane's A-row (row = lr)
    int jb[4];
    #pragma unroll
    for (int e = 0; e < 4; ++e) jb[e] = __shfl(best_idx[e], (lr >> 2) * 16);
    int rsel = lr & 3;
    int jm = jb[0];
    if (rsel == 1) jm = jb[1];
    else if (rsel == 2) jm = jb[2];
    else if (rsel == 3) jm = jb[3];

    // ---- quantize gather/write + diff partial (x rebuilt from ah+al) ----
    float dsum = 0.f;
    const float* qrow = embT + (size_t)jm * DIM + lg * 8;
    float* qout = out + OFF_Q + (size_t)myrow * DIM + lg * 8;
    #pragma unroll
    for (int kf = 0; kf < 8; ++kf) {
        f32x4 q0 = *(const f32x4*)(qrow + kf * 32);
        f32x4 q1 = *(const f32x4*)(qrow + kf * 32 + 4);
        *(f32x4*)(qout + kf * 32) = q0;
        *(f32x4*)(qout + kf * 32 + 4) = q1;
        #pragma unroll
        for (int i = 0; i < 4; ++i) {
            float x0 = (float)ah[kf][i] + (float)al[kf][i];
            float x1 = (float)ah[kf][4 + i] + (float)al[kf][4 + i];
            float d0 = q0[i] - x0, d1 = q1[i] - x1;
            dsum += d0 * d0 + d1 * d1;
        }
    }
    for (int off = 32; off; off >>= 1) dsum += __shfl_down(dsum, off);
    if (l == 0) dred[w] = dsum;
    __syncthreads();
    if (tid == 0) diffpart[blockIdx.x] = dred[0] + dred[1] + dred[2] + dred[3];
}

// ---------------- K2: shfl-scan + EMA scalars + diff finalize (1 block, 1024 thr) ----
__global__ void k2_small(const float* __restrict__ cluster_size,
                         const int* __restrict__ counts,
                         const float* __restrict__ diffpart,
                         float* __restrict__ out,
                         int* __restrict__ offsets,
                         float* __restrict__ cs_ws) {
    __shared__ int   wtot[16];
    __shared__ float wsum[16], wdiff[16];
    int t = threadIdx.x, w = t >> 6, l = t & 63;
    int cnt = counts[t];
    float ncs = cluster_size[t] * DECAY + ONE_MINUS * (float)cnt;
    out[OFF_NCS + t] = ncs;

    int sc = cnt;
    #pragma unroll
    for (int off = 1; off < 64; off <<= 1) {
        int v = __shfl_up(sc, off);
        if (l >= off) sc += v;
    }
    float ws = ncs;
    float dp = diffpart[t] + diffpart[t + 1024];   // k1 grid = 2048 blocks
    #pragma unroll
    for (int off = 32; off; off >>= 1) {
        ws += __shfl_xor(ws, off);
        dp += __shfl_xor(dp, off);
    }
    if (l == 63) wtot[w] = sc;
    if (l == 0) { wsum[w] = ws; wdiff[w] = dp; }
    __syncthreads();
    int woff = 0; float n = 0.f, dtot = 0.f;
    #pragma unroll
    for (int i = 0; i < 16; ++i) {
        woff += (i < w) ? wtot[i] : 0;
        n += wsum[i];
        dtot += wdiff[i];
    }
    offsets[t] = woff + sc - cnt;       // exclusive prefix
    cs_ws[t] = (ncs + EPS) / (n + (float)NE * EPS) * n;
    if (t == 0) out[OFF_DIFF] = dtot / 33554432.0f;
}

// ---------------- K3: scatter row ids into per-code buckets ----------------
__global__ void k3_scatter(const int* __restrict__ jint,
                           const int* __restrict__ offsets,
                           int* __restrict__ cursors,
                           int* __restrict__ list) {
    int r = blockIdx.x * 256 + threadIdx.x;
    int j = jint[r];
    int pos = atomicAdd(&cursors[j], 1);
    list[offsets[j] + pos] = r;
}

// ---------------- K4: BALANCED segment sum over sorted list ----------------
#define K4FLUSH() do {                                                   \
    float* dst = embed_sum + (size_t)curj * DIM + l * 4;                 \
    atomicAdd(dst + 0, acc[0]); atomicAdd(dst + 1, acc[1]);              \
    atomicAdd(dst + 2, acc[2]); atomicAdd(dst + 3, acc[3]);              \
    acc[0] = acc[1] = acc[2] = acc[3] = 0.f;                             \
} while (0)

__global__ void k4_segsum(const float* __restrict__ input,
                          const int* __restrict__ jint,
                          const int* __restrict__ list,
                          float* __restrict__ embed_sum) {
    int wid = (blockIdx.x * 256 + threadIdx.x) >> 6;   // 0..4095
    int l = threadIdx.x & 63;
    int p0 = wid * 32;
    int row_l = list[p0 + (l & 31)];
    int j_l = jint[row_l];
    f32x4 acc = {0.f, 0.f, 0.f, 0.f};
    int curj = __shfl(j_l, 0);
    #pragma unroll 1
    for (int g = 0; g < 8; ++g) {
        int r0 = __shfl(row_l, 4 * g + 0), j0 = __shfl(j_l, 4 * g + 0);
        int r1 = __shfl(row_l, 4 * g + 1), j1 = __shfl(j_l, 4 * g + 1);
        int r2 = __shfl(row_l, 4 * g + 2), j2 = __shfl(j_l, 4 * g + 2);
        int r3 = __shfl(row_l, 4 * g + 3), j3 = __shfl(j_l, 4 * g + 3);
        f32x4 v0 = *(const f32x4*)(input + (size_t)r0 * DIM + l * 4);
        f32x4 v1 = *(const f32x4*)(input + (size_t)r1 * DIM + l * 4);
        f32x4 v2 = *(const f32x4*)(input + (size_t)r2 * DIM + l * 4);
        f32x4 v3 = *(const f32x4*)(input + (size_t)r3 * DIM + l * 4);
        if (j0 != curj) { K4FLUSH(); curj = j0; }
        acc += v0;
        if (j1 != curj) { K4FLUSH(); curj = j1; }
        acc += v1;
        if (j2 != curj) { K4FLUSH(); curj = j2; }
        acc += v2;
        if (j3 != curj) { K4FLUSH(); curj = j3; }
        acc += v3;
    }
    K4FLUSH();
}

// ---------------- K5: transpose + EMA outputs (LDS-tiled, coalesced) ----------
__global__ void k5_ema(const float* __restrict__ embed_sum,
                       const float* __restrict__ embed_avg,
                       const float* __restrict__ cs_ws,
                       float* __restrict__ out) {
    __shared__ float T[64][65];
    int t = threadIdx.x;
    int j0 = blockIdx.x * 64, d0 = blockIdx.y * 64;
    #pragma unroll
    for (int p = 0; p < 16; ++p) {
        int jj = p * 4 + (t >> 6), dd = t & 63;
        T[dd][jj] = embed_sum[(size_t)(j0 + jj) * DIM + d0 + dd];
    }
    __syncthreads();
    #pragma unroll
    for (int p = 0; p < 16; ++p) {
        int dd = p * 4 + (t >> 6), jj = t & 63;
        int d = d0 + dd, j = j0 + jj;
        float sum = T[dd][jj];
        float na = embed_avg[(size_t)d * NE + j] * DECAY + ONE_MINUS * sum;
        out[OFF_NEA + (size_t)d * NE + j] = na;
        out[OFF_NEMB + (size_t)d * NE + j] = na / cs_ws[j];
    }
}

extern "C" void kernel_launch(void* const* d_in, const int* in_sizes, int n_in,
                              void* d_out, int out_size, void* d_ws, size_t ws_size,
                              hipStream_t stream) {
    const float* input        = (const float*)d_in[0];
    const float* embed        = (const float*)d_in[1];
    const float* cluster_size = (const float*)d_in[2];
    const float* embed_avg    = (const float*)d_in[3];
    float* out = (float*)d_out;
    char* ws = (char*)d_ws;

    _Float16* bt_hi  = (_Float16*)(ws + 0);
    float*    embT   = (float*)(ws + 1048576);
    float*    sqh    = (float*)(ws + 2097152);
    int*      counts = (int*)(ws + 2101248);
    int*      offsets= (int*)(ws + 2105344);
    int*      cursors= (int*)(ws + 2113536);
    int*      jint   = (int*)(ws + 2117632);
    int*      list   = (int*)(ws + 2641920);
    float*    diffpart = (float*)(ws + 3166208);   // 2048 floats
    float*    cs_ws  = (float*)(ws + 3174400);
    // k4/k5 run after k1 is done with bt_hi: reuse that region
    float*    embed_sum = (float*)(ws + 0);   // [1024][256] f32

    hipMemsetAsync(counts, 0, 4096, stream);
    hipMemsetAsync(cursors, 0, 4096, stream);

    k0_prep<<<dim3(16, 4), 256, 0, stream>>>(embed, bt_hi, embT);
    k0b_sq<<<256, 256, 0, stream>>>(embT, sqh);
    k1_main<<<2048, 256, 0, stream>>>(input, bt_hi, embT, sqh, out, jint, counts, diffpart);
    // bt_hi dead after k1 -> zero that region for embed_sum accumulation
    hipMemsetAsync(embed_sum, 0, (size_t)NE * DIM * sizeof(float), stream);
    k2_small<<<1, 1024, 0, stream>>>(cluster_size, counts, diffpart, out, offsets, cs_ws);
    k3_scatter<<<512, 256, 0, stream>>>(jint, offsets, cursors, list);
    k4_segsum<<<1024, 256, 0, stream>>>(input, jint, list, embed_sum);
    k5_ema<<<dim3(16, 4), 256, 0, stream>>>(embed_sum, embed_avg, cs_ws, out);
}

// Round 8
// 325.384 us; speedup vs baseline: 1.8770x; 1.4258x over previous
//
#include <hip/hip_runtime.h>

typedef _Float16 half8 __attribute__((ext_vector_type(8)));
typedef float f32x4 __attribute__((ext_vector_type(4)));

#define DIM 256
#define NE 1024
#define NROWS 131072
#define DECAY 0.99f
#define ONE_MINUS 0.01f
#define EPS 1e-5f

// output offsets (floats) in d_out, concatenated in reference return order
#define OFF_Q    0u
#define OFF_DIFF 33554432u
#define OFF_IND  33554433u
#define OFF_NEMB 33685505u
#define OFF_NCS  33947649u
#define OFF_NEA  33948673u

#define GLOAD16(gp, lp) __builtin_amdgcn_global_load_lds( \
    (__attribute__((address_space(1))) const void*)(gp),  \
    (__attribute__((address_space(3))) void*)(lp), 16, 0, 0)

#define MFMA16(a, b, c) __builtin_amdgcn_mfma_f32_16x16x32_f16(a, b, c, 0, 0, 0)

// ---------------- K0: codebook transpose (LDS-tiled, coalesced both sides) ----
// embed [256][1024] -> bt_hi [1024][256] f16 hi plane + embT [1024][256] f32
__global__ void k0_prep(const float* __restrict__ embed,
                        _Float16* __restrict__ bt_hi,
                        float* __restrict__ embT) {
    __shared__ float T[64][65];
    int t = threadIdx.x;
    int j0 = blockIdx.x * 64, d0 = blockIdx.y * 64;
    #pragma unroll
    for (int p = 0; p < 16; ++p) {
        int dd = p * 4 + (t >> 6), jj = t & 63;
        T[jj][dd] = embed[(size_t)(d0 + dd) * NE + j0 + jj];
    }
    __syncthreads();
    #pragma unroll
    for (int p = 0; p < 16; ++p) {
        int jj = p * 4 + (t >> 6), dd = t & 63;
        float e = T[jj][dd];
        int j = j0 + jj, d = d0 + dd;
        embT[(size_t)j * DIM + d] = e;
        bt_hi[(size_t)j * DIM + d] = (_Float16)e;
    }
}

// ---------------- K0b: sqh[j] = 0.5*||e_j||^2 (exact f32) ----------------
__global__ void k0b_sq(const float* __restrict__ embT, float* __restrict__ sqh) {
    int w = threadIdx.x >> 6, l = threadIdx.x & 63;
    int j = blockIdx.x * 4 + w;
    f32x4 v = *(const f32x4*)(embT + (size_t)j * DIM + l * 4);
    float s = v[0] * v[0] + v[1] * v[1] + v[2] * v[2] + v[3] * v[3];
    for (int off = 32; off; off >>= 1) s += __shfl_down(s, off);
    if (l == 0) sqh[j] = 0.5f * s;
}

// ---------------- K1: distance GEMM (16x16x32, hi-A x hi-B) + argmin + ... ----
// x.e ~= ah.bh (1-term; error sigma ~3e-3 vs best-vs-2nd gaps of O(8); absmax
// headroom measured in R7). Live regs ~90 -> fits 128 cap; waves_per_eu pinned
// to 4 so the allocator cannot target 8 waves and spill (R6/R7 failure mode).
__global__ __launch_bounds__(256)
__attribute__((amdgpu_waves_per_eu(4, 4)))
void k1_main(const float* __restrict__ input,
             const _Float16* __restrict__ bt_hi,
             const float* __restrict__ embT,
             const float* __restrict__ sqh,
             float* __restrict__ out,
             int* __restrict__ jint,
             int* __restrict__ counts,
             float* __restrict__ diffpart) {
    __shared__ _Float16 Bbuf[2][16][256];   // [buf][code-row][k]  16 KB
    __shared__ float sq_lds[NE];            // 4 KB
    __shared__ float dred[4];

    const int tid = threadIdx.x;
    const int w  = tid >> 6;       // wave 0..3
    const int l  = tid & 63;       // lane
    const int lr = l & 15;         // M-row (A) / N-col (B) within fragment
    const int lg = l >> 4;         // k-group (0..3)
    const int s7 = lr & 7;         // read-swizzle term
    const int row0 = blockIdx.x * 64 + w * 16;
    const int myrow = row0 + lr;

    // stage addressing: wave stages 2 x 1KB per chunk (hi plane only)
    const int r0 = 2 * w + (l >> 5);        // dest row 0..7
    const int g0 = (l & 31) ^ r0;           // source granule (inverse swizzle)
    const int s0 = r0 * 256 + g0 * 8;       // f16 offset within chunk
    const int s1 = s0 + 2048;               // rows 8..15

#define STAGE(cc, b) do {                                             \
    const _Float16* hp_ = bt_hi + (((size_t)(cc)) << 12);             \
    GLOAD16(hp_ + s0, &Bbuf[b][2 * w][0]);                            \
    GLOAD16(hp_ + s1, &Bbuf[b][8 + 2 * w][0]);                        \
} while (0)

    STAGE(0, 0);
    STAGE(1, 1);

    for (int i = tid; i < NE; i += 256) sq_lds[i] = sqh[i];

    // A load: lane holds row lr, dims {kf*32 + lg*8 + 0..7}, f16 hi only.
    // Fully unrolled: all indices compile-time (rule #20).
    half8 ah[8];
    {
        const float* arow = input + (size_t)myrow * DIM + lg * 8;
        #pragma unroll
        for (int kf = 0; kf < 8; ++kf) {
            f32x4 x0 = *(const f32x4*)(arow + kf * 32);
            f32x4 x1 = *(const f32x4*)(arow + kf * 32 + 4);
            half8 hh;
            #pragma unroll
            for (int i = 0; i < 4; ++i) {
                hh[i]     = (_Float16)x0[i];
                hh[4 + i] = (_Float16)x1[i];
            }
            ah[kf] = hh;
        }
    }

    float best_val[4];
    int   best_idx[4];
    #pragma unroll
    for (int e = 0; e < 4; ++e) { best_val[e] = 3.4e38f; best_idx[e] = 0; }

    __syncthreads();   // one-time full drain: chunks 0,1 + sq_lds + A loads

    const int rb = lr * 256;
    int buf = 0;
    #pragma unroll 1
    for (int c = 0; c < 64; ++c) {
        // own 2 chunk-c loads landed; chunk c+1's stay in flight
        if (c == 63) { asm volatile("s_waitcnt vmcnt(0)" ::: "memory"); }
        else         { asm volatile("s_waitcnt vmcnt(2)" ::: "memory"); }
        __builtin_amdgcn_s_barrier();

        const _Float16* BH = &Bbuf[buf][0][0];

        f32x4 acc0 = {0.f,0.f,0.f,0.f}, acc1 = {0.f,0.f,0.f,0.f};
        f32x4 acc2 = {0.f,0.f,0.f,0.f}, acc3 = {0.f,0.f,0.f,0.f};

        __builtin_amdgcn_s_setprio(1);
        {   // kf 0..3: 4 reads, 4 MFMAs (4 independent chains)
            half8 b0 = *(const half8*)(BH + rb + (((0 << 2) | lg) ^ s7) * 8);
            half8 b1 = *(const half8*)(BH + rb + (((1 << 2) | lg) ^ s7) * 8);
            half8 b2 = *(const half8*)(BH + rb + (((2 << 2) | lg) ^ s7) * 8);
            half8 b3 = *(const half8*)(BH + rb + (((3 << 2) | lg) ^ s7) * 8);
            acc0 = MFMA16(ah[0], b0, acc0);
            acc1 = MFMA16(ah[1], b1, acc1);
            acc2 = MFMA16(ah[2], b2, acc2);
            acc3 = MFMA16(ah[3], b3, acc3);
        }
        {   // kf 4..7
            half8 b0 = *(const half8*)(BH + rb + (((4 << 2) | lg) ^ s7) * 8);
            half8 b1 = *(const half8*)(BH + rb + (((5 << 2) | lg) ^ s7) * 8);
            half8 b2 = *(const half8*)(BH + rb + (((6 << 2) | lg) ^ s7) * 8);
            half8 b3 = *(const half8*)(BH + rb + (((7 << 2) | lg) ^ s7) * 8);
            acc0 = MFMA16(ah[4], b0, acc0);
            acc1 = MFMA16(ah[5], b1, acc1);
            acc2 = MFMA16(ah[6], b2, acc2);
            acc3 = MFMA16(ah[7], b3, acc3);
        }
        __builtin_amdgcn_s_setprio(0);
        __builtin_amdgcn_s_barrier();   // all waves done reading Bbuf[buf]

        // stage chunk c+2 into the buffer just consumed
        if (c < 62) STAGE(c + 2, buf);

        // register-only argmin update
        const int col = (c << 4) + lr;
        float sq = sq_lds[col];
        f32x4 dot = (acc0 + acc1) + (acc2 + acc3);
        #pragma unroll
        for (int e = 0; e < 4; ++e) {
            float v = sq - dot[e];
            if (v < best_val[e]) { best_val[e] = v; best_idx[e] = col; }
        }

        buf ^= 1;
    }

    // ---- cross-lane argmin within each 16-lane group (rows lg*4+e) ----
    #pragma unroll
    for (int e = 0; e < 4; ++e) {
        float v = best_val[e]; int ix = best_idx[e];
        #pragma unroll
        for (int off = 1; off < 16; off <<= 1) {
            float ov = __shfl_xor(v, off);
            int   oi = __shfl_xor(ix, off);
            if (ov < v || (ov == v && oi < ix)) { v = ov; ix = oi; }
        }
        best_val[e] = v; best_idx[e] = ix;
    }

    if (lr == 0) {
        #pragma unroll
        for (int e = 0; e < 4; ++e) {
            int grow = row0 + lg * 4 + e;
            int j = best_idx[e];
            out[OFF_IND + grow] = (float)j;
            jint[grow] = j;
            atomicAdd(&counts[j], 1);
        }
    }

    // winning code for THIS lane's A-row (row = lr)
    int jb[4];
    #pragma unroll
    for (int e = 0; e < 4; ++e) jb[e] = __shfl(best_idx[e], (lr >> 2) * 16);
    int rsel = lr & 3;
    int jm = jb[0];
    if (rsel == 1) jm = jb[1];
    else if (rsel == 2) jm = jb[2];
    else if (rsel == 3) jm = jb[3];

    // ---- quantize gather/write + diff partial (x ~ ah; residue ~1e-4 washes
    //      out in the 33.5M-element mean) ----
    float dsum = 0.f;
    const float* qrow = embT + (size_t)jm * DIM + lg * 8;
    float* qout = out + OFF_Q + (size_t)myrow * DIM + lg * 8;
    #pragma unroll
    for (int kf = 0; kf < 8; ++kf) {
        f32x4 q0 = *(const f32x4*)(qrow + kf * 32);
        f32x4 q1 = *(const f32x4*)(qrow + kf * 32 + 4);
        *(f32x4*)(qout + kf * 32) = q0;
        *(f32x4*)(qout + kf * 32 + 4) = q1;
        #pragma unroll
        for (int i = 0; i < 4; ++i) {
            float d0 = q0[i] - (float)ah[kf][i];
            float d1 = q1[i] - (float)ah[kf][4 + i];
            dsum += d0 * d0 + d1 * d1;
        }
    }
    for (int off = 32; off; off >>= 1) dsum += __shfl_down(dsum, off);
    if (l == 0) dred[w] = dsum;
    __syncthreads();
    if (tid == 0) diffpart[blockIdx.x] = dred[0] + dred[1] + dred[2] + dred[3];
}

// ---------------- K2: shfl-scan + EMA scalars + diff finalize (1 block, 1024 thr) ----
__global__ void k2_small(const float* __restrict__ cluster_size,
                         const int* __restrict__ counts,
                         const float* __restrict__ diffpart,
                         float* __restrict__ out,
                         int* __restrict__ offsets,
                         float* __restrict__ cs_ws) {
    __shared__ int   wtot[16];
    __shared__ float wsum[16], wdiff[16];
    int t = threadIdx.x, w = t >> 6, l = t & 63;
    int cnt = counts[t];
    float ncs = cluster_size[t] * DECAY + ONE_MINUS * (float)cnt;
    out[OFF_NCS + t] = ncs;

    int sc = cnt;
    #pragma unroll
    for (int off = 1; off < 64; off <<= 1) {
        int v = __shfl_up(sc, off);
        if (l >= off) sc += v;
    }
    float ws = ncs;
    float dp = diffpart[t] + diffpart[t + 1024];   // k1 grid = 2048 blocks
    #pragma unroll
    for (int off = 32; off; off >>= 1) {
        ws += __shfl_xor(ws, off);
        dp += __shfl_xor(dp, off);
    }
    if (l == 63) wtot[w] = sc;
    if (l == 0) { wsum[w] = ws; wdiff[w] = dp; }
    __syncthreads();
    int woff = 0; float n = 0.f, dtot = 0.f;
    #pragma unroll
    for (int i = 0; i < 16; ++i) {
        woff += (i < w) ? wtot[i] : 0;
        n += wsum[i];
        dtot += wdiff[i];
    }
    offsets[t] = woff + sc - cnt;       // exclusive prefix
    cs_ws[t] = (ncs + EPS) / (n + (float)NE * EPS) * n;
    if (t == 0) out[OFF_DIFF] = dtot / 33554432.0f;
}

// ---------------- K3: scatter row ids into per-code buckets ----------------
__global__ void k3_scatter(const int* __restrict__ jint,
                           const int* __restrict__ offsets,
                           int* __restrict__ cursors,
                           int* __restrict__ list) {
    int r = blockIdx.x * 256 + threadIdx.x;
    int j = jint[r];
    int pos = atomicAdd(&cursors[j], 1);
    list[offsets[j] + pos] = r;
}

// ---------------- K4: BALANCED segment sum over sorted list ----------------
#define K4FLUSH() do {                                                   \
    float* dst = embed_sum + (size_t)curj * DIM + l * 4;                 \
    atomicAdd(dst + 0, acc[0]); atomicAdd(dst + 1, acc[1]);              \
    atomicAdd(dst + 2, acc[2]); atomicAdd(dst + 3, acc[3]);              \
    acc[0] = acc[1] = acc[2] = acc[3] = 0.f;                             \
} while (0)

__global__ void k4_segsum(const float* __restrict__ input,
                          const int* __restrict__ jint,
                          const int* __restrict__ list,
                          float* __restrict__ embed_sum) {
    int wid = (blockIdx.x * 256 + threadIdx.x) >> 6;   // 0..4095
    int l = threadIdx.x & 63;
    int p0 = wid * 32;
    int row_l = list[p0 + (l & 31)];
    int j_l = jint[row_l];
    f32x4 acc = {0.f, 0.f, 0.f, 0.f};
    int curj = __shfl(j_l, 0);
    #pragma unroll 1
    for (int g = 0; g < 8; ++g) {
        int r0 = __shfl(row_l, 4 * g + 0), j0 = __shfl(j_l, 4 * g + 0);
        int r1 = __shfl(row_l, 4 * g + 1), j1 = __shfl(j_l, 4 * g + 1);
        int r2 = __shfl(row_l, 4 * g + 2), j2 = __shfl(j_l, 4 * g + 2);
        int r3 = __shfl(row_l, 4 * g + 3), j3 = __shfl(j_l, 4 * g + 3);
        f32x4 v0 = *(const f32x4*)(input + (size_t)r0 * DIM + l * 4);
        f32x4 v1 = *(const f32x4*)(input + (size_t)r1 * DIM + l * 4);
        f32x4 v2 = *(const f32x4*)(input + (size_t)r2 * DIM + l * 4);
        f32x4 v3 = *(const f32x4*)(input + (size_t)r3 * DIM + l * 4);
        if (j0 != curj) { K4FLUSH(); curj = j0; }
        acc += v0;
        if (j1 != curj) { K4FLUSH(); curj = j1; }
        acc += v1;
        if (j2 != curj) { K4FLUSH(); curj = j2; }
        acc += v2;
        if (j3 != curj) { K4FLUSH(); curj = j3; }
        acc += v3;
    }
    K4FLUSH();
}

// ---------------- K5: transpose + EMA outputs (LDS-tiled, coalesced) ----------
__global__ void k5_ema(const float* __restrict__ embed_sum,
                       const float* __restrict__ embed_avg,
                       const float* __restrict__ cs_ws,
                       float* __restrict__ out) {
    __shared__ float T[64][65];
    int t = threadIdx.x;
    int j0 = blockIdx.x * 64, d0 = blockIdx.y * 64;
    #pragma unroll
    for (int p = 0; p < 16; ++p) {
        int jj = p * 4 + (t >> 6), dd = t & 63;
        T[dd][jj] = embed_sum[(size_t)(j0 + jj) * DIM + d0 + dd];
    }
    __syncthreads();
    #pragma unroll
    for (int p = 0; p < 16; ++p) {
        int dd = p * 4 + (t >> 6), jj = t & 63;
        int d = d0 + dd, j = j0 + jj;
        float sum = T[dd][jj];
        float na = embed_avg[(size_t)d * NE + j] * DECAY + ONE_MINUS * sum;
        out[OFF_NEA + (size_t)d * NE + j] = na;
        out[OFF_NEMB + (size_t)d * NE + j] = na / cs_ws[j];
    }
}

extern "C" void kernel_launch(void* const* d_in, const int* in_sizes, int n_in,
                              void* d_out, int out_size, void* d_ws, size_t ws_size,
                              hipStream_t stream) {
    const float* input        = (const float*)d_in[0];
    const float* embed        = (const float*)d_in[1];
    const float* cluster_size = (const float*)d_in[2];
    const float* embed_avg    = (const float*)d_in[3];
    float* out = (float*)d_out;
    char* ws = (char*)d_ws;

    _Float16* bt_hi  = (_Float16*)(ws + 0);
    float*    embT   = (float*)(ws + 1048576);
    float*    sqh    = (float*)(ws + 2097152);
    int*      counts = (int*)(ws + 2101248);
    int*      offsets= (int*)(ws + 2105344);
    int*      cursors= (int*)(ws + 2113536);
    int*      jint   = (int*)(ws + 2117632);
    int*      list   = (int*)(ws + 2641920);
    float*    diffpart = (float*)(ws + 3166208);   // 2048 floats
    float*    cs_ws  = (float*)(ws + 3174400);
    // k4/k5 run after k1 is done with bt_hi: reuse that region
    float*    embed_sum = (float*)(ws + 0);   // [1024][256] f32

    hipMemsetAsync(counts, 0, 4096, stream);
    hipMemsetAsync(cursors, 0, 4096, stream);

    k0_prep<<<dim3(16, 4), 256, 0, stream>>>(embed, bt_hi, embT);
    k0b_sq<<<256, 256, 0, stream>>>(embT, sqh);
    k1_main<<<2048, 256, 0, stream>>>(input, bt_hi, embT, sqh, out, jint, counts, diffpart);
    // bt_hi dead after k1 -> zero that region for embed_sum accumulation
    hipMemsetAsync(embed_sum, 0, (size_t)NE * DIM * sizeof(float), stream);
    k2_small<<<1, 1024, 0, stream>>>(cluster_size, counts, diffpart, out, offsets, cs_ws);
    k3_scatter<<<512, 256, 0, stream>>>(jint, offsets, cursors, list);
    k4_segsum<<<1024, 256, 0, stream>>>(input, jint, list, embed_sum);
    k5_ema<<<dim3(16, 4), 256, 0, stream>>>(embed_sum, embed_avg, cs_ws, out);
}